// Round 1
// baseline (617.990 us; speedup 1.0000x reference)
//
#include <hip/hip_runtime.h>
#include <math.h>

#define B_  8
#define N_  1024
#define DM  512
#define H_  8
#define DK_ 64
#define ST  128
#define QT  32

// ---------------------------------------------------------------------------
// GEMM: C[M=8192][512] = A[M][512] * W[512][512]^T  (+ bias + resid if FUSE)
// 64x64 tile per block, 256 threads, 4x4 per thread, BK=16, k-major LDS.
// ---------------------------------------------------------------------------
template<bool FUSE>
__global__ __launch_bounds__(256)
void gemm512_kernel(const float* __restrict__ A, const float* __restrict__ W,
                    const float* __restrict__ bias, const float* __restrict__ resid,
                    float* __restrict__ C)
{
    __shared__ __align__(16) float As[16][68];
    __shared__ __align__(16) float Ws[16][68];
    const int tid = threadIdx.x;
    const int tx = tid & 15, ty = tid >> 4;
    const int bm = blockIdx.x, bn = blockIdx.y;
    const int lrow = tid >> 2;           // 0..63
    const int lk4  = (tid & 3) << 2;     // 0,4,8,12
    const float* Ag = A + (size_t)(bm * 64 + lrow) * 512 + lk4;
    const float* Wg = W + (size_t)(bn * 64 + lrow) * 512 + lk4;
    float acc[4][4] = {};
    for (int kt = 0; kt < 512; kt += 16) {
        float4 a4 = *(const float4*)(Ag + kt);
        float4 w4 = *(const float4*)(Wg + kt);
        __syncthreads();
        As[lk4 + 0][lrow] = a4.x; As[lk4 + 1][lrow] = a4.y;
        As[lk4 + 2][lrow] = a4.z; As[lk4 + 3][lrow] = a4.w;
        Ws[lk4 + 0][lrow] = w4.x; Ws[lk4 + 1][lrow] = w4.y;
        Ws[lk4 + 2][lrow] = w4.z; Ws[lk4 + 3][lrow] = w4.w;
        __syncthreads();
        #pragma unroll
        for (int kk = 0; kk < 16; ++kk) {
            float4 av = *(const float4*)&As[kk][ty << 2];
            float4 wv = *(const float4*)&Ws[kk][tx << 2];
            float a_[4] = {av.x, av.y, av.z, av.w};
            float w_[4] = {wv.x, wv.y, wv.z, wv.w};
            #pragma unroll
            for (int r = 0; r < 4; ++r)
                #pragma unroll
                for (int c = 0; c < 4; ++c)
                    acc[r][c] = fmaf(a_[r], w_[c], acc[r][c]);
        }
    }
    const int row0 = bm * 64 + (ty << 2);
    const int col0 = bn * 64 + (tx << 2);
    #pragma unroll
    for (int r = 0; r < 4; ++r) {
        float4 o;
        o.x = acc[r][0]; o.y = acc[r][1]; o.z = acc[r][2]; o.w = acc[r][3];
        if (FUSE) {
            float4 bi = *(const float4*)&bias[col0];
            float4 rs = *(const float4*)&resid[(size_t)(row0 + r) * DM + col0];
            o.x += bi.x + rs.x; o.y += bi.y + rs.y;
            o.z += bi.z + rs.z; o.w += bi.w + rs.w;
        }
        *(float4*)&C[(size_t)(row0 + r) * DM + col0] = o;
    }
}

// ---------------------------------------------------------------------------
// Star-sparse attention with RPE.
// Block = (32 queries) x (head h) x (batch b), 256 threads.
// Exact vs dense reference: masked entries underflow to 0 in softmax.
// ---------------------------------------------------------------------------
__global__ __launch_bounds__(256)
void attn_kernel(const float* __restrict__ q, const float* __restrict__ k,
                 const float* __restrict__ v, const float* __restrict__ rpe,
                 float* __restrict__ ctx)
{
    __shared__ __align__(16) float Qs[64][34];      //  8.7 KB  Qs[d][qr]
    __shared__ __align__(16) float KV[128 * 68];    // 34.8 KB  K-phase [64][132], V-phase [128][68]
    __shared__ __align__(16) float Ps[128][34];     // 17.4 KB  Ps[j][qr]
    __shared__ float selfS[QT];

    const int tid = threadIdx.x;
    const int tx = tid & 15, ty = tid >> 4;
    const int qb = blockIdx.x * QT;
    const int h  = blockIdx.y;
    const int b  = blockIdx.z;

    const float* qg = q + (size_t)(b * N_ + qb) * DM + h * DK_;   // row stride DM
    const float* kg = k + (size_t)b * N_ * DM + h * DK_;
    const float* vg = v + (size_t)b * N_ * DM + h * DK_;

    // ---- load Q tile (d-major) ----
    {
        const int row = tid >> 3;             // 0..31
        const int kc  = (tid & 7) << 3;       // 0..56
        float4 a  = *(const float4*)(qg + (size_t)row * DM + kc);
        float4 bq = *(const float4*)(qg + (size_t)row * DM + kc + 4);
        Qs[kc + 0][row] = a.x;  Qs[kc + 1][row] = a.y;
        Qs[kc + 2][row] = a.z;  Qs[kc + 3][row] = a.w;
        Qs[kc + 4][row] = bq.x; Qs[kc + 5][row] = bq.y;
        Qs[kc + 6][row] = bq.z; Qs[kc + 7][row] = bq.w;
    }
    // ---- load K station (d-major: KV[d*132 + j]) ----
    #pragma unroll
    for (int it = 0; it < 8; ++it) {
        int id = tid + it * 256;
        int j  = id >> 4;                 // 0..127
        int dc = (id & 15) << 2;          // 0..60
        float4 a = *(const float4*)(kg + (size_t)j * DM + dc);
        KV[(dc + 0) * 132 + j] = a.x;
        KV[(dc + 1) * 132 + j] = a.y;
        KV[(dc + 2) * 132 + j] = a.z;
        KV[(dc + 3) * 132 + j] = a.w;
    }
    __syncthreads();

    // ---- self-loop scores (lanes 0..31 of wave 0) ----
    if (tid < QT) {
        int i = qb + tid;
        float sv = -1e30f;
        if (i >= ST) {
            float dot = 0.f;
            const float* krow = kg + (size_t)i * DM;
            for (int d = 0; d < DK_; ++d)
                dot = fmaf(Qs[d][tid], krow[d], dot);
            sv = (dot + rpe[((size_t)(b * H_ + h) * N_ + i) * N_ + i]) * 0.125f;
        }
        selfS[tid] = sv;
    }

    // ---- score GEMM: s[q=ty*2+r][j=tx*8+c] ----
    float s[2][8] = {};
    #pragma unroll 4
    for (int d = 0; d < 64; ++d) {
        float2 qv = *(const float2*)&Qs[d][ty << 1];
        float4 ka = *(const float4*)&KV[d * 132 + (tx << 3)];
        float4 kb = *(const float4*)&KV[d * 132 + (tx << 3) + 4];
        float kk_[8] = {ka.x, ka.y, ka.z, ka.w, kb.x, kb.y, kb.z, kb.w};
        #pragma unroll
        for (int c = 0; c < 8; ++c) {
            s[0][c] = fmaf(qv.x, kk_[c], s[0][c]);
            s[1][c] = fmaf(qv.y, kk_[c], s[1][c]);
        }
    }
    __syncthreads();   // selfS visible; all K reads done

    // ---- rpe + scale + softmax (m,l stay in registers) ----
    float l_r[2], ps_r[2];
    #pragma unroll
    for (int r = 0; r < 2; ++r) {
        int i = qb + (ty << 1) + r;
        const float* rrow = rpe + ((size_t)(b * H_ + h) * N_ + i) * N_ + (tx << 3);
        float4 ra = *(const float4*)rrow;
        float4 rb = *(const float4*)(rrow + 4);
        float rr[8] = {ra.x, ra.y, ra.z, ra.w, rb.x, rb.y, rb.z, rb.w};
        float mx = -1e30f;
        #pragma unroll
        for (int c = 0; c < 8; ++c) {
            s[r][c] = (s[r][c] + rr[c]) * 0.125f;
            mx = fmaxf(mx, s[r][c]);
        }
        #pragma unroll
        for (int o = 1; o < 16; o <<= 1)
            mx = fmaxf(mx, __shfl_xor(mx, o, 64));
        float sm = selfS[(ty << 1) + r];
        mx = fmaxf(mx, sm);
        float ls = 0.f;
        float p[8];
        #pragma unroll
        for (int c = 0; c < 8; ++c) {
            p[c] = __expf(s[r][c] - mx);
            ls += p[c];
        }
        #pragma unroll
        for (int o = 1; o < 16; o <<= 1)
            ls += __shfl_xor(ls, o, 64);
        float pself = __expf(sm - mx);    // exactly 0 when i < ST
        ls += pself;
        l_r[r] = ls; ps_r[r] = pself;
        #pragma unroll
        for (int c = 0; c < 8; ++c)
            Ps[(tx << 3) + c][(ty << 1) + r] = p[c];
    }
    __syncthreads();

    // ---- load V station (j-major: KV[j*68 + d]), overwrites K buffer ----
    #pragma unroll
    for (int it = 0; it < 8; ++it) {
        int id = tid + it * 256;
        int j  = id >> 4;
        int dc = (id & 15) << 2;
        float4 a = *(const float4*)(vg + (size_t)j * DM + dc);
        *(float4*)&KV[j * 68 + dc] = a;
    }
    __syncthreads();

    // ---- AV GEMM: ctx[q][d=tx*4+c] ----
    float c2[2][4] = {};
    #pragma unroll 4
    for (int j = 0; j < 128; ++j) {
        float2 pv = *(const float2*)&Ps[j][ty << 1];
        float4 vv = *(const float4*)&KV[j * 68 + (tx << 2)];
        float vv_[4] = {vv.x, vv.y, vv.z, vv.w};
        #pragma unroll
        for (int c = 0; c < 4; ++c) {
            c2[0][c] = fmaf(pv.x, vv_[c], c2[0][c]);
            c2[1][c] = fmaf(pv.y, vv_[c], c2[1][c]);
        }
    }
    // ---- self-loop V, normalize, store ----
    #pragma unroll
    for (int r = 0; r < 2; ++r) {
        int qr = (ty << 1) + r;
        int i  = qb + qr;
        if (i >= ST) {
            float4 sv4 = *(const float4*)(vg + (size_t)i * DM + (tx << 2));
            float pself = ps_r[r];
            c2[r][0] = fmaf(pself, sv4.x, c2[r][0]);
            c2[r][1] = fmaf(pself, sv4.y, c2[r][1]);
            c2[r][2] = fmaf(pself, sv4.z, c2[r][2]);
            c2[r][3] = fmaf(pself, sv4.w, c2[r][3]);
        }
        float inv = 1.0f / l_r[r];
        float4 o = make_float4(c2[r][0] * inv, c2[r][1] * inv,
                               c2[r][2] * inv, c2[r][3] * inv);
        *(float4*)&ctx[(size_t)(b * N_ + i) * DM + h * DK_ + (tx << 2)] = o;
    }
}

// ---------------------------------------------------------------------------
// LayerNorm over D=512, in-place on d_out (pre-LN values from FC epilogue).
// ---------------------------------------------------------------------------
__global__ __launch_bounds__(256)
void ln_kernel(float* __restrict__ io, const float* __restrict__ g,
               const float* __restrict__ bb)
{
    const int t = blockIdx.x;
    const int tid = threadIdx.x;
    float* row = io + (size_t)t * DM;
    float2 x = *(const float2*)&row[tid * 2];
    float s  = x.x + x.y;
    float ss = fmaf(x.x, x.x, x.y * x.y);
    #pragma unroll
    for (int o = 1; o < 64; o <<= 1) {
        s  += __shfl_xor(s,  o, 64);
        ss += __shfl_xor(ss, o, 64);
    }
    __shared__ float wsum[4], wsq[4];
    const int w = tid >> 6;
    if ((tid & 63) == 0) { wsum[w] = s; wsq[w] = ss; }
    __syncthreads();
    s  = wsum[0] + wsum[1] + wsum[2] + wsum[3];
    ss = wsq[0]  + wsq[1]  + wsq[2]  + wsq[3];
    const float mean = s * (1.0f / DM);
    const float var  = ss * (1.0f / DM) - mean * mean;
    const float rstd = rsqrtf(var + 1e-6f);
    float2 gg = *(const float2*)&g[tid * 2];
    float2 bv = *(const float2*)&bb[tid * 2];
    x.x = (x.x - mean) * rstd * gg.x + bv.x;
    x.y = (x.y - mean) * rstd * gg.y + bv.y;
    *(float2*)&row[tid * 2] = x;
}

// ---------------------------------------------------------------------------
extern "C" void kernel_launch(void* const* d_in, const int* in_sizes, int n_in,
                              void* d_out, int out_size, void* d_ws, size_t ws_size,
                              hipStream_t stream)
{
    (void)in_sizes; (void)n_in; (void)out_size; (void)ws_size;
    const float* hidden = (const float*)d_in[0];
    const float* rpe    = (const float*)d_in[1];
    const float* Wq     = (const float*)d_in[2];
    const float* Wk     = (const float*)d_in[3];
    const float* Wv     = (const float*)d_in[4];
    const float* fc_w   = (const float*)d_in[5];
    const float* fc_b   = (const float*)d_in[6];
    const float* ln_g   = (const float*)d_in[7];
    const float* ln_b   = (const float*)d_in[8];
    float* out = (float*)d_out;
    float* ws  = (float*)d_ws;

    const size_t SZ = (size_t)B_ * N_ * DM;   // 4,194,304 floats
    float* qb = ws;
    float* kb = ws + SZ;
    float* vb = ws + 2 * SZ;
    float* cb = ws + 3 * SZ;

    dim3 gg(8192 / 64, DM / 64);
    gemm512_kernel<false><<<gg, 256, 0, stream>>>(hidden, Wq, nullptr, nullptr, qb);
    gemm512_kernel<false><<<gg, 256, 0, stream>>>(hidden, Wk, nullptr, nullptr, kb);
    gemm512_kernel<false><<<gg, 256, 0, stream>>>(hidden, Wv, nullptr, nullptr, vb);
    attn_kernel<<<dim3(N_ / QT, H_, B_), 256, 0, stream>>>(qb, kb, vb, rpe, cb);
    gemm512_kernel<true><<<gg, 256, 0, stream>>>(cb, fc_w, fc_b, hidden, out);
    ln_kernel<<<B_ * N_, 256, 0, stream>>>(out, ln_g, ln_b);
}

// Round 2
// 426.549 us; speedup vs baseline: 1.4488x; 1.4488x over previous
//
#include <hip/hip_runtime.h>
#include <hip/hip_bf16.h>
#include <math.h>

#define B_  8
#define N_  1024
#define DM  512
#define H_  8
#define DK_ 64
#define ST  128
#define QT  32

typedef __attribute__((ext_vector_type(8))) short short8;
typedef __attribute__((ext_vector_type(4))) float floatx4;

#define GLD16(gp, lp)                                                          \
    __builtin_amdgcn_global_load_lds(                                          \
        (const __attribute__((address_space(1))) void*)(gp),                   \
        (__attribute__((address_space(3))) void*)(lp), 16, 0, 0)

// ---------------------------------------------------------------------------
// Cast fp32 -> bf16 (RNE), 5 jobs selected by blockIdx.y.
// ---------------------------------------------------------------------------
struct CastArgs {
    const float* src[5];
    unsigned short* dst[5];
    int n[5];
};

__global__ __launch_bounds__(256)
void cast_bf16_kernel(CastArgs a)
{
    const int j = blockIdx.y;
    const float* __restrict__ s = a.src[j];
    unsigned short* __restrict__ d = a.dst[j];
    const int n = a.n[j];
    int i = (blockIdx.x * 256 + threadIdx.x) * 8;
    if (i >= n) return;
    float4 x0 = *(const float4*)&s[i];
    float4 x1 = *(const float4*)&s[i + 4];
    ushort4 o0, o1;
    __hip_bfloat16 t;
    t = __float2bfloat16(x0.x); o0.x = *(unsigned short*)&t;
    t = __float2bfloat16(x0.y); o0.y = *(unsigned short*)&t;
    t = __float2bfloat16(x0.z); o0.z = *(unsigned short*)&t;
    t = __float2bfloat16(x0.w); o0.w = *(unsigned short*)&t;
    t = __float2bfloat16(x1.x); o1.x = *(unsigned short*)&t;
    t = __float2bfloat16(x1.y); o1.y = *(unsigned short*)&t;
    t = __float2bfloat16(x1.z); o1.z = *(unsigned short*)&t;
    t = __float2bfloat16(x1.w); o1.w = *(unsigned short*)&t;
    *(ushort4*)&d[i] = o0;
    *(ushort4*)&d[i + 4] = o1;
}

// ---------------------------------------------------------------------------
// MFMA GEMM core: C[M][512] = A[M][512] * W[512][512]^T, bf16 in, fp32 out.
// 128x128 tile, BK=32, 256 threads (4 waves, 2x2), 4x4 16x16x32 MFMA per wave.
// A,W both k-contiguous (row-major, 512 stride).
// ---------------------------------------------------------------------------
__device__ __forceinline__
void gemm_core(const unsigned short* __restrict__ A,
               const unsigned short* __restrict__ W,
               int m0, int n0, unsigned short* As, unsigned short* Bs,
               floatx4 acc[4][4])
{
    const int tid = threadIdx.x;
    const int lane = tid & 63;
    const int wave = tid >> 6;
    const int wm = wave >> 1, wn = wave & 1;
    const int srow = tid >> 2;          // 0..63
    const int skq  = (tid & 3) * 8;     // 0,8,16,24
    const unsigned short* Ag = A + (size_t)(m0 + srow) * 512 + skq;
    const unsigned short* Bg = W + (size_t)(n0 + srow) * 512 + skq;
    const int mrow = lane & 15;
    const int koff = (lane >> 4) * 8;

    for (int kt = 0; kt < 512; kt += 32) {
        __syncthreads();
        GLD16(Ag + kt,            &As[tid * 8]);
        GLD16(Ag + 64 * 512 + kt, &As[2048 + tid * 8]);
        GLD16(Bg + kt,            &Bs[tid * 8]);
        GLD16(Bg + 64 * 512 + kt, &Bs[2048 + tid * 8]);
        __syncthreads();
        short8 af[4], bf[4];
        #pragma unroll
        for (int t = 0; t < 4; ++t) {
            af[t] = *(const short8*)&As[(wm * 64 + t * 16 + mrow) * 32 + koff];
            bf[t] = *(const short8*)&Bs[(wn * 64 + t * 16 + mrow) * 32 + koff];
        }
        #pragma unroll
        for (int mt = 0; mt < 4; ++mt)
            #pragma unroll
            for (int nt = 0; nt < 4; ++nt)
                acc[mt][nt] = __builtin_amdgcn_mfma_f32_16x16x32_bf16(
                    af[mt], bf[nt], acc[mt][nt], 0, 0, 0);
    }
}

// Fused QKV: blockIdx.y in [0,12): y>>2 selects weight/output, (y&3)*128 = n0.
__global__ __launch_bounds__(256)
void qkv_gemm_kernel(const unsigned short* __restrict__ A,
                     const unsigned short* __restrict__ W0,
                     const unsigned short* __restrict__ W1,
                     const unsigned short* __restrict__ W2,
                     float* __restrict__ q, float* __restrict__ k,
                     float* __restrict__ v)
{
    __shared__ __align__(16) unsigned short As[128 * 32];
    __shared__ __align__(16) unsigned short Bs[128 * 32];
    const int by = blockIdx.y;
    const unsigned short* W = (by < 4) ? W0 : (by < 8 ? W1 : W2);
    float* C = (by < 4) ? q : (by < 8 ? k : v);
    const int m0 = blockIdx.x * 128;
    const int n0 = (by & 3) * 128;

    floatx4 acc[4][4];
    #pragma unroll
    for (int i = 0; i < 4; ++i)
        #pragma unroll
        for (int j = 0; j < 4; ++j)
            acc[i][j] = (floatx4){0.f, 0.f, 0.f, 0.f};

    gemm_core(A, W, m0, n0, As, Bs, acc);

    const int lane = threadIdx.x & 63;
    const int wave = threadIdx.x >> 6;
    const int wm = wave >> 1, wn = wave & 1;
    const int col = n0 + wn * 64 + (lane & 15);
    const int rq  = (lane >> 4) * 4;
    #pragma unroll
    for (int mt = 0; mt < 4; ++mt)
        #pragma unroll
        for (int nt = 0; nt < 4; ++nt)
            #pragma unroll
            for (int r = 0; r < 4; ++r)
                C[(size_t)(m0 + wm * 64 + mt * 16 + rq + r) * 512 + col + nt * 16]
                    = acc[mt][nt][r];
}

// FC: out = A*W^T + bias + resid (fp32 out, pre-LN).
__global__ __launch_bounds__(256)
void fc_gemm_kernel(const unsigned short* __restrict__ A,
                    const unsigned short* __restrict__ W,
                    const float* __restrict__ bias,
                    const float* __restrict__ resid,
                    float* __restrict__ C)
{
    __shared__ __align__(16) unsigned short As[128 * 32];
    __shared__ __align__(16) unsigned short Bs[128 * 32];
    const int m0 = blockIdx.x * 128;
    const int n0 = blockIdx.y * 128;

    floatx4 acc[4][4];
    #pragma unroll
    for (int i = 0; i < 4; ++i)
        #pragma unroll
        for (int j = 0; j < 4; ++j)
            acc[i][j] = (floatx4){0.f, 0.f, 0.f, 0.f};

    gemm_core(A, W, m0, n0, As, Bs, acc);

    const int lane = threadIdx.x & 63;
    const int wave = threadIdx.x >> 6;
    const int wm = wave >> 1, wn = wave & 1;
    const int col = n0 + wn * 64 + (lane & 15);
    const int rq  = (lane >> 4) * 4;
    #pragma unroll
    for (int mt = 0; mt < 4; ++mt)
        #pragma unroll
        for (int nt = 0; nt < 4; ++nt) {
            const int c = col + nt * 16;
            const float b = bias[c];
            #pragma unroll
            for (int r = 0; r < 4; ++r) {
                const size_t row = (size_t)(m0 + wm * 64 + mt * 16 + rq + r);
                C[row * 512 + c] = acc[mt][nt][r] + b + resid[row * 512 + c];
            }
        }
}

// ---------------------------------------------------------------------------
// Star-sparse attention with RPE (fp32 q/k/v in, bf16 ctx out).
// Block = (32 queries) x (head h) x (batch b), 256 threads.
// ---------------------------------------------------------------------------
__global__ __launch_bounds__(256)
void attn_kernel(const float* __restrict__ q, const float* __restrict__ k,
                 const float* __restrict__ v, const float* __restrict__ rpe,
                 unsigned short* __restrict__ ctx)
{
    __shared__ __align__(16) float Qs[64][34];
    __shared__ __align__(16) float KV[128 * 68];
    __shared__ __align__(16) float Ps[128][34];
    __shared__ float selfS[QT];

    const int tid = threadIdx.x;
    const int tx = tid & 15, ty = tid >> 4;
    const int qb = blockIdx.x * QT;
    const int h  = blockIdx.y;
    const int b  = blockIdx.z;

    const float* qg = q + (size_t)(b * N_ + qb) * DM + h * DK_;
    const float* kg = k + (size_t)b * N_ * DM + h * DK_;
    const float* vg = v + (size_t)b * N_ * DM + h * DK_;

    {
        const int row = tid >> 3;
        const int kc  = (tid & 7) << 3;
        float4 a  = *(const float4*)(qg + (size_t)row * DM + kc);
        float4 bq = *(const float4*)(qg + (size_t)row * DM + kc + 4);
        Qs[kc + 0][row] = a.x;  Qs[kc + 1][row] = a.y;
        Qs[kc + 2][row] = a.z;  Qs[kc + 3][row] = a.w;
        Qs[kc + 4][row] = bq.x; Qs[kc + 5][row] = bq.y;
        Qs[kc + 6][row] = bq.z; Qs[kc + 7][row] = bq.w;
    }
    #pragma unroll
    for (int it = 0; it < 8; ++it) {
        int id = tid + it * 256;
        int j  = id >> 4;
        int dc = (id & 15) << 2;
        float4 a = *(const float4*)(kg + (size_t)j * DM + dc);
        KV[(dc + 0) * 132 + j] = a.x;
        KV[(dc + 1) * 132 + j] = a.y;
        KV[(dc + 2) * 132 + j] = a.z;
        KV[(dc + 3) * 132 + j] = a.w;
    }
    __syncthreads();

    if (tid < QT) {
        int i = qb + tid;
        float sv = -1e30f;
        if (i >= ST) {
            float dot = 0.f;
            const float* krow = kg + (size_t)i * DM;
            for (int d = 0; d < DK_; ++d)
                dot = fmaf(Qs[d][tid], krow[d], dot);
            sv = (dot + rpe[((size_t)(b * H_ + h) * N_ + i) * N_ + i]) * 0.125f;
        }
        selfS[tid] = sv;
    }

    float s[2][8] = {};
    #pragma unroll 4
    for (int d = 0; d < 64; ++d) {
        float2 qv = *(const float2*)&Qs[d][ty << 1];
        float4 ka = *(const float4*)&KV[d * 132 + (tx << 3)];
        float4 kb = *(const float4*)&KV[d * 132 + (tx << 3) + 4];
        float kk_[8] = {ka.x, ka.y, ka.z, ka.w, kb.x, kb.y, kb.z, kb.w};
        #pragma unroll
        for (int c = 0; c < 8; ++c) {
            s[0][c] = fmaf(qv.x, kk_[c], s[0][c]);
            s[1][c] = fmaf(qv.y, kk_[c], s[1][c]);
        }
    }
    __syncthreads();

    float l_r[2], ps_r[2];
    #pragma unroll
    for (int r = 0; r < 2; ++r) {
        int i = qb + (ty << 1) + r;
        const float* rrow = rpe + ((size_t)(b * H_ + h) * N_ + i) * N_ + (tx << 3);
        float4 ra = *(const float4*)rrow;
        float4 rb = *(const float4*)(rrow + 4);
        float rr[8] = {ra.x, ra.y, ra.z, ra.w, rb.x, rb.y, rb.z, rb.w};
        float mx = -1e30f;
        #pragma unroll
        for (int c = 0; c < 8; ++c) {
            s[r][c] = (s[r][c] + rr[c]) * 0.125f;
            mx = fmaxf(mx, s[r][c]);
        }
        #pragma unroll
        for (int o = 1; o < 16; o <<= 1)
            mx = fmaxf(mx, __shfl_xor(mx, o, 64));
        float sm = selfS[(ty << 1) + r];
        mx = fmaxf(mx, sm);
        float ls = 0.f;
        float p[8];
        #pragma unroll
        for (int c = 0; c < 8; ++c) {
            p[c] = __expf(s[r][c] - mx);
            ls += p[c];
        }
        #pragma unroll
        for (int o = 1; o < 16; o <<= 1)
            ls += __shfl_xor(ls, o, 64);
        float pself = __expf(sm - mx);
        ls += pself;
        l_r[r] = ls; ps_r[r] = pself;
        #pragma unroll
        for (int c = 0; c < 8; ++c)
            Ps[(tx << 3) + c][(ty << 1) + r] = p[c];
    }
    __syncthreads();

    #pragma unroll
    for (int it = 0; it < 8; ++it) {
        int id = tid + it * 256;
        int j  = id >> 4;
        int dc = (id & 15) << 2;
        float4 a = *(const float4*)(vg + (size_t)j * DM + dc);
        *(float4*)&KV[j * 68 + dc] = a;
    }
    __syncthreads();

    float c2[2][4] = {};
    #pragma unroll 4
    for (int j = 0; j < 128; ++j) {
        float2 pv = *(const float2*)&Ps[j][ty << 1];
        float4 vv = *(const float4*)&KV[j * 68 + (tx << 2)];
        float vv_[4] = {vv.x, vv.y, vv.z, vv.w};
        #pragma unroll
        for (int c = 0; c < 4; ++c) {
            c2[0][c] = fmaf(pv.x, vv_[c], c2[0][c]);
            c2[1][c] = fmaf(pv.y, vv_[c], c2[1][c]);
        }
    }
    #pragma unroll
    for (int r = 0; r < 2; ++r) {
        int qr = (ty << 1) + r;
        int i  = qb + qr;
        if (i >= ST) {
            float4 sv4 = *(const float4*)(vg + (size_t)i * DM + (tx << 2));
            float pself = ps_r[r];
            c2[r][0] = fmaf(pself, sv4.x, c2[r][0]);
            c2[r][1] = fmaf(pself, sv4.y, c2[r][1]);
            c2[r][2] = fmaf(pself, sv4.z, c2[r][2]);
            c2[r][3] = fmaf(pself, sv4.w, c2[r][3]);
        }
        float inv = 1.0f / l_r[r];
        ushort4 o;
        __hip_bfloat16 t;
        t = __float2bfloat16(c2[r][0] * inv); o.x = *(unsigned short*)&t;
        t = __float2bfloat16(c2[r][1] * inv); o.y = *(unsigned short*)&t;
        t = __float2bfloat16(c2[r][2] * inv); o.z = *(unsigned short*)&t;
        t = __float2bfloat16(c2[r][3] * inv); o.w = *(unsigned short*)&t;
        *(ushort4*)&ctx[(size_t)(b * N_ + i) * DM + h * DK_ + (tx << 2)] = o;
    }
}

// ---------------------------------------------------------------------------
// LayerNorm over D=512, in-place on d_out.
// ---------------------------------------------------------------------------
__global__ __launch_bounds__(256)
void ln_kernel(float* __restrict__ io, const float* __restrict__ g,
               const float* __restrict__ bb)
{
    const int t = blockIdx.x;
    const int tid = threadIdx.x;
    float* row = io + (size_t)t * DM;
    float2 x = *(const float2*)&row[tid * 2];
    float s  = x.x + x.y;
    float ss = fmaf(x.x, x.x, x.y * x.y);
    #pragma unroll
    for (int o = 1; o < 64; o <<= 1) {
        s  += __shfl_xor(s,  o, 64);
        ss += __shfl_xor(ss, o, 64);
    }
    __shared__ float wsum[4], wsq[4];
    const int w = tid >> 6;
    if ((tid & 63) == 0) { wsum[w] = s; wsq[w] = ss; }
    __syncthreads();
    s  = wsum[0] + wsum[1] + wsum[2] + wsum[3];
    ss = wsq[0]  + wsq[1]  + wsq[2]  + wsq[3];
    const float mean = s * (1.0f / DM);
    const float var  = ss * (1.0f / DM) - mean * mean;
    const float rstd = rsqrtf(var + 1e-6f);
    float2 gg = *(const float2*)&g[tid * 2];
    float2 bv = *(const float2*)&bb[tid * 2];
    x.x = (x.x - mean) * rstd * gg.x + bv.x;
    x.y = (x.y - mean) * rstd * gg.y + bv.y;
    *(float2*)&row[tid * 2] = x;
}

// ---------------------------------------------------------------------------
extern "C" void kernel_launch(void* const* d_in, const int* in_sizes, int n_in,
                              void* d_out, int out_size, void* d_ws, size_t ws_size,
                              hipStream_t stream)
{
    (void)in_sizes; (void)n_in; (void)out_size; (void)ws_size;
    const float* hidden = (const float*)d_in[0];
    const float* rpe    = (const float*)d_in[1];
    const float* Wq     = (const float*)d_in[2];
    const float* Wk     = (const float*)d_in[3];
    const float* Wv     = (const float*)d_in[4];
    const float* fc_w   = (const float*)d_in[5];
    const float* fc_b   = (const float*)d_in[6];
    const float* ln_g   = (const float*)d_in[7];
    const float* ln_b   = (const float*)d_in[8];
    float* out = (float*)d_out;
    char* ws = (char*)d_ws;

    const size_t MB = 1024 * 1024;
    float*          qb = (float*)(ws + 0 * MB);     // 16 MB
    float*          kb = (float*)(ws + 16 * MB);    // 16 MB
    float*          vb = (float*)(ws + 32 * MB);    // 16 MB
    unsigned short* hb = (unsigned short*)(ws + 48 * MB);   // 8 MB
    unsigned short* cb = (unsigned short*)(ws + 56 * MB);   // 8 MB
    unsigned short* wq = (unsigned short*)(ws + 64 * MB);
    unsigned short* wk = (unsigned short*)(ws + 64 * MB + 512 * 1024);
    unsigned short* wv = (unsigned short*)(ws + 65 * MB);
    unsigned short* wf = (unsigned short*)(ws + 65 * MB + 512 * 1024);

    CastArgs ca;
    ca.src[0] = hidden; ca.dst[0] = hb; ca.n[0] = B_ * N_ * DM;
    ca.src[1] = Wq;     ca.dst[1] = wq; ca.n[1] = DM * DM;
    ca.src[2] = Wk;     ca.dst[2] = wk; ca.n[2] = DM * DM;
    ca.src[3] = Wv;     ca.dst[3] = wv; ca.n[3] = DM * DM;
    ca.src[4] = fc_w;   ca.dst[4] = wf; ca.n[4] = DM * DM;
    cast_bf16_kernel<<<dim3(2048, 5), 256, 0, stream>>>(ca);

    qkv_gemm_kernel<<<dim3(64, 12), 256, 0, stream>>>(hb, wq, wk, wv, qb, kb, vb);
    attn_kernel<<<dim3(N_ / QT, H_, B_), 256, 0, stream>>>(qb, kb, vb, rpe, cb);
    fc_gemm_kernel<<<dim3(64, 4), 256, 0, stream>>>(cb, wf, fc_b, hidden, out);
    ln_kernel<<<B_ * N_, 256, 0, stream>>>(out, ln_g, ln_b);
}

// Round 3
// 400.239 us; speedup vs baseline: 1.5441x; 1.0657x over previous
//
#include <hip/hip_runtime.h>
#include <hip/hip_bf16.h>
#include <math.h>

#define B_  8
#define N_  1024
#define DM  512
#define H_  8
#define DK_ 64
#define ST  128

typedef __attribute__((ext_vector_type(8))) short short8;
typedef __attribute__((ext_vector_type(4))) float floatx4;

#define GLD16(gp, lp)                                                          \
    __builtin_amdgcn_global_load_lds(                                          \
        (const __attribute__((address_space(1))) void*)(gp),                   \
        (__attribute__((address_space(3))) void*)(lp), 16, 0, 0)

__device__ __forceinline__ float b2f(short u) {
    union { unsigned int i; float f; } c;
    c.i = ((unsigned int)(unsigned short)u) << 16;
    return c.f;
}
__device__ __forceinline__ unsigned short f2b(float f) {
    __hip_bfloat16 t = __float2bfloat16(f);
    return *(unsigned short*)&t;
}

// ---------------------------------------------------------------------------
// Cast fp32 -> bf16 (RNE), 5 jobs selected by blockIdx.y.
// ---------------------------------------------------------------------------
struct CastArgs {
    const float* src[5];
    unsigned short* dst[5];
    int n[5];
};

__global__ __launch_bounds__(256)
void cast_bf16_kernel(CastArgs a)
{
    const int j = blockIdx.y;
    const float* __restrict__ s = a.src[j];
    unsigned short* __restrict__ d = a.dst[j];
    const int n = a.n[j];
    int i = (blockIdx.x * 256 + threadIdx.x) * 8;
    if (i >= n) return;
    float4 x0 = *(const float4*)&s[i];
    float4 x1 = *(const float4*)&s[i + 4];
    ushort4 o0, o1;
    o0.x = f2b(x0.x); o0.y = f2b(x0.y); o0.z = f2b(x0.z); o0.w = f2b(x0.w);
    o1.x = f2b(x1.x); o1.y = f2b(x1.y); o1.z = f2b(x1.z); o1.w = f2b(x1.w);
    *(ushort4*)&d[i] = o0;
    *(ushort4*)&d[i + 4] = o1;
}

// ---------------------------------------------------------------------------
// MFMA GEMM core: 128x128 tile, BK=32, 256 threads (4 waves 2x2), bf16 in.
// ---------------------------------------------------------------------------
__device__ __forceinline__
void gemm_core(const unsigned short* __restrict__ A,
               const unsigned short* __restrict__ W,
               int m0, int n0, unsigned short* As, unsigned short* Bs,
               floatx4 acc[4][4])
{
    const int tid = threadIdx.x;
    const int lane = tid & 63;
    const int wave = tid >> 6;
    const int wm = wave >> 1, wn = wave & 1;
    const int srow = tid >> 2;
    const int skq  = (tid & 3) * 8;
    const unsigned short* Ag = A + (size_t)(m0 + srow) * 512 + skq;
    const unsigned short* Bg = W + (size_t)(n0 + srow) * 512 + skq;
    const int mrow = lane & 15;
    const int koff = (lane >> 4) * 8;

    for (int kt = 0; kt < 512; kt += 32) {
        __syncthreads();
        GLD16(Ag + kt,            &As[tid * 8]);
        GLD16(Ag + 64 * 512 + kt, &As[2048 + tid * 8]);
        GLD16(Bg + kt,            &Bs[tid * 8]);
        GLD16(Bg + 64 * 512 + kt, &Bs[2048 + tid * 8]);
        __syncthreads();
        short8 af[4], bf[4];
        #pragma unroll
        for (int t = 0; t < 4; ++t) {
            af[t] = *(const short8*)&As[(wm * 64 + t * 16 + mrow) * 32 + koff];
            bf[t] = *(const short8*)&Bs[(wn * 64 + t * 16 + mrow) * 32 + koff];
        }
        #pragma unroll
        for (int mt = 0; mt < 4; ++mt)
            #pragma unroll
            for (int nt = 0; nt < 4; ++nt)
                acc[mt][nt] = __builtin_amdgcn_mfma_f32_16x16x32_bf16(
                    af[mt], bf[nt], acc[mt][nt], 0, 0, 0);
    }
}

// ---------------------------------------------------------------------------
// Fused QKV GEMM. Outputs bf16: q,k as [B,H,N,64]; v transposed [B,H,64,N].
// blockIdx.y in [0,12): y>>2 selects q/k/v, (y&3)*128 = n0.
// ---------------------------------------------------------------------------
__global__ __launch_bounds__(256)
void qkv_gemm_kernel(const unsigned short* __restrict__ A,
                     const unsigned short* __restrict__ W0,
                     const unsigned short* __restrict__ W1,
                     const unsigned short* __restrict__ W2,
                     unsigned short* __restrict__ qo,
                     unsigned short* __restrict__ ko,
                     unsigned short* __restrict__ vto)
{
    __shared__ __align__(16) unsigned short As[128 * 32];
    __shared__ __align__(16) unsigned short Bs[128 * 32];
    const int by = blockIdx.y;
    const int sel = by >> 2;
    const unsigned short* W = (sel == 0) ? W0 : (sel == 1 ? W1 : W2);
    const int m0 = blockIdx.x * 128;
    const int n0 = (by & 3) * 128;

    floatx4 acc[4][4];
    #pragma unroll
    for (int i = 0; i < 4; ++i)
        #pragma unroll
        for (int j = 0; j < 4; ++j)
            acc[i][j] = (floatx4){0.f, 0.f, 0.f, 0.f};

    gemm_core(A, W, m0, n0, As, Bs, acc);

    const int lane = threadIdx.x & 63;
    const int wave = threadIdx.x >> 6;
    const int wm = wave >> 1, wn = wave & 1;
    const int lx = lane & 15;
    const int rq = (lane >> 4) * 4;

    if (sel == 2) {
        // V transposed: [B,H,64,N] — r-direction is token-contiguous.
        #pragma unroll
        for (int mt = 0; mt < 4; ++mt) {
            const int mrow = m0 + wm * 64 + mt * 16 + rq;
            const int bb = mrow >> 10, tok = mrow & 1023;
            #pragma unroll
            for (int nt = 0; nt < 4; ++nt) {
                const int c = n0 + wn * 64 + nt * 16 + lx;
                const int hh = c >> 6, d = c & 63;
                ushort4 pk;
                pk.x = f2b(acc[mt][nt][0]); pk.y = f2b(acc[mt][nt][1]);
                pk.z = f2b(acc[mt][nt][2]); pk.w = f2b(acc[mt][nt][3]);
                *(ushort4*)&vto[((size_t)(bb * H_ + hh) * DK_ + d) * N_ + tok] = pk;
            }
        }
    } else {
        unsigned short* O = (sel == 0) ? qo : ko;
        #pragma unroll
        for (int mt = 0; mt < 4; ++mt) {
            const int mrow = m0 + wm * 64 + mt * 16 + rq;
            const int bb = mrow >> 10, tok = mrow & 1023;
            #pragma unroll
            for (int nt = 0; nt < 4; ++nt) {
                const int c = n0 + wn * 64 + nt * 16 + lx;
                const int hh = c >> 6, d = c & 63;
                unsigned short* p =
                    O + ((size_t)(bb * H_ + hh) * N_ + tok) * DK_ + d;
                #pragma unroll
                for (int r = 0; r < 4; ++r)
                    p[(size_t)r * DK_] = f2b(acc[mt][nt][r]);
            }
        }
    }
}

// ---------------------------------------------------------------------------
// FC: out = A*W^T + bias + resid (fp32 out, pre-LN).
// ---------------------------------------------------------------------------
__global__ __launch_bounds__(256)
void fc_gemm_kernel(const unsigned short* __restrict__ A,
                    const unsigned short* __restrict__ W,
                    const float* __restrict__ bias,
                    const float* __restrict__ resid,
                    float* __restrict__ C)
{
    __shared__ __align__(16) unsigned short As[128 * 32];
    __shared__ __align__(16) unsigned short Bs[128 * 32];
    const int m0 = blockIdx.x * 128;
    const int n0 = blockIdx.y * 128;

    floatx4 acc[4][4];
    #pragma unroll
    for (int i = 0; i < 4; ++i)
        #pragma unroll
        for (int j = 0; j < 4; ++j)
            acc[i][j] = (floatx4){0.f, 0.f, 0.f, 0.f};

    gemm_core(A, W, m0, n0, As, Bs, acc);

    const int lane = threadIdx.x & 63;
    const int wave = threadIdx.x >> 6;
    const int wm = wave >> 1, wn = wave & 1;
    const int col = n0 + wn * 64 + (lane & 15);
    const int rq  = (lane >> 4) * 4;
    #pragma unroll
    for (int mt = 0; mt < 4; ++mt)
        #pragma unroll
        for (int nt = 0; nt < 4; ++nt) {
            const int c = col + nt * 16;
            const float b = bias[c];
            #pragma unroll
            for (int r = 0; r < 4; ++r) {
                const size_t row = (size_t)(m0 + wm * 64 + mt * 16 + rq + r);
                C[row * 512 + c] = acc[mt][nt][r] + b + resid[row * 512 + c];
            }
        }
}

// ---------------------------------------------------------------------------
// Star-sparse MFMA attention. Block = (64 queries) x head x batch, 256 thr.
// Wave w owns query rows [w*16, w*16+16) x all 128 station cols.
// q,k: bf16 [B,H,N,64]; v: bf16 transposed [B,H,64,N]. LDS only for P.
// Masked cols (j>=128, j!=i) underflow to 0 in the dense reference softmax,
// so station cols + (self for i>=128) is exact.
// ---------------------------------------------------------------------------
__global__ __launch_bounds__(256)
void attn_kernel(const unsigned short* __restrict__ qg,
                 const unsigned short* __restrict__ kg,
                 const unsigned short* __restrict__ vtg,
                 const float* __restrict__ rpe,
                 unsigned short* __restrict__ ctx)
{
    __shared__ __align__(16) unsigned short P[64 * 136];   // 17.4 KB

    const int tid  = threadIdx.x;
    const int lane = tid & 63;
    const int w    = tid >> 6;
    const int lx   = lane & 15;
    const int quad = lane >> 4;
    const int qb = blockIdx.x * 64;
    const int h  = blockIdx.y, b = blockIdx.z;
    const int bh = b * H_ + h;
    const unsigned short* qh  = qg  + (size_t)bh * N_ * DK_;
    const unsigned short* kh  = kg  + (size_t)bh * N_ * DK_;
    const unsigned short* vth = vtg + (size_t)bh * DK_ * N_;
    const float* rp = rpe + ((size_t)bh * N_ + qb) * N_;   // local row i -> rp[i*N_]
    const bool has_self = (qb >= ST);

    // ---- self-loop score: lane covers row (w*16+lx), d-quarter quad ----
    float sself = -1e30f;
    if (has_self) {
        const int i = qb + w * 16 + lx;
        const unsigned short* qr = qh + (size_t)i * DK_ + quad * 16;
        const unsigned short* kr = kh + (size_t)i * DK_ + quad * 16;
        short8 q0 = *(const short8*)qr, q1 = *(const short8*)(qr + 8);
        short8 k0 = *(const short8*)kr, k1 = *(const short8*)(kr + 8);
        float dot = 0.f;
        #pragma unroll
        for (int j = 0; j < 8; ++j) {
            dot = fmaf(b2f(q0[j]), b2f(k0[j]), dot);
            dot = fmaf(b2f(q1[j]), b2f(k1[j]), dot);
        }
        dot += __shfl_xor(dot, 16, 64);
        dot += __shfl_xor(dot, 32, 64);
        const float rd = rp[(size_t)(w * 16 + lx) * N_ + (qb + w * 16 + lx)];
        sself = (dot + rd) * 0.125f;
    }

    // ---- rpe prefetch: lane covers rows (w*16+quad*4+r), cols nt*16+lx ----
    float rv[4][8];
    {
        const float* rbase = rp + (size_t)(w * 16 + quad * 4) * N_ + lx;
        #pragma unroll
        for (int r = 0; r < 4; ++r)
            #pragma unroll
            for (int nt = 0; nt < 8; ++nt)
                rv[r][nt] = rbase[(size_t)r * N_ + nt * 16];
    }

    // ---- S = Q*K^T (A,B frags straight from global) ----
    short8 aq[2];
    {
        const unsigned short* qrow =
            qh + (size_t)(qb + w * 16 + lx) * DK_ + quad * 8;
        aq[0] = *(const short8*)qrow;
        aq[1] = *(const short8*)(qrow + 32);
    }
    floatx4 sacc[8];
    #pragma unroll
    for (int nt = 0; nt < 8; ++nt) sacc[nt] = (floatx4){0.f, 0.f, 0.f, 0.f};
    #pragma unroll
    for (int nt = 0; nt < 8; ++nt) {
        const unsigned short* krow =
            kh + (size_t)(nt * 16 + lx) * DK_ + quad * 8;
        short8 b0 = *(const short8*)krow;
        short8 b1 = *(const short8*)(krow + 32);
        sacc[nt] = __builtin_amdgcn_mfma_f32_16x16x32_bf16(aq[0], b0, sacc[nt], 0, 0, 0);
        sacc[nt] = __builtin_amdgcn_mfma_f32_16x16x32_bf16(aq[1], b1, sacc[nt], 0, 0, 0);
    }

    // ---- softmax (fully in-wave; rows = w*16 + quad*4 + r) ----
    float l4[4], ps4[4];
    #pragma unroll
    for (int r = 0; r < 4; ++r) {
        float sv[8];
        float mx = -1e30f;
        #pragma unroll
        for (int nt = 0; nt < 8; ++nt) {
            sv[nt] = (sacc[nt][r] + rv[r][nt]) * 0.125f;
            mx = fmaxf(mx, sv[nt]);
        }
        #pragma unroll
        for (int o = 1; o < 16; o <<= 1)
            mx = fmaxf(mx, __shfl_xor(mx, o, 64));
        const float ss = __shfl(sself, quad * 4 + r, 64);
        mx = fmaxf(mx, ss);
        float sum = 0.f;
        #pragma unroll
        for (int nt = 0; nt < 8; ++nt) {
            sv[nt] = __expf(sv[nt] - mx);
            sum += sv[nt];
        }
        #pragma unroll
        for (int o = 1; o < 16; o <<= 1)
            sum += __shfl_xor(sum, o, 64);
        const float ps = has_self ? __expf(ss - mx) : 0.f;
        l4[r] = sum + ps;
        ps4[r] = ps;
        const int row = w * 16 + quad * 4 + r;
        #pragma unroll
        for (int nt = 0; nt < 8; ++nt)
            P[row * 136 + nt * 16 + lx] = f2b(sv[nt]);
    }
    __syncthreads();

    // ---- O = P*V (A frags from LDS, B frags from global vT) ----
    short8 ap[4];
    #pragma unroll
    for (int ks = 0; ks < 4; ++ks)
        ap[ks] = *(const short8*)&P[(w * 16 + lx) * 136 + ks * 32 + quad * 8];
    floatx4 oacc[4];
    #pragma unroll
    for (int nt = 0; nt < 4; ++nt) oacc[nt] = (floatx4){0.f, 0.f, 0.f, 0.f};
    #pragma unroll
    for (int nt = 0; nt < 4; ++nt) {
        const unsigned short* vrow = vth + (size_t)(nt * 16 + lx) * N_;
        #pragma unroll
        for (int ks = 0; ks < 4; ++ks) {
            short8 bv = *(const short8*)(vrow + ks * 32 + quad * 8);
            oacc[nt] = __builtin_amdgcn_mfma_f32_16x16x32_bf16(ap[ks], bv, oacc[nt], 0, 0, 0);
        }
    }

    // ---- self V + normalize + store ctx bf16 [B*N][512] ----
    #pragma unroll
    for (int r = 0; r < 4; ++r) {
        const int i = qb + w * 16 + quad * 4 + r;
        const float inv = 1.0f / l4[r];
        const float ps = ps4[r];
        #pragma unroll
        for (int nt = 0; nt < 4; ++nt) {
            const int d = nt * 16 + lx;
            float o = oacc[nt][r];
            if (has_self)
                o = fmaf(ps, b2f((short)vth[(size_t)d * N_ + i]), o);
            ctx[((size_t)(b * N_) + i) * DM + h * DK_ + d] = f2b(o * inv);
        }
    }
}

// ---------------------------------------------------------------------------
// LayerNorm over D=512, in-place on d_out.
// ---------------------------------------------------------------------------
__global__ __launch_bounds__(256)
void ln_kernel(float* __restrict__ io, const float* __restrict__ g,
               const float* __restrict__ bb)
{
    const int t = blockIdx.x;
    const int tid = threadIdx.x;
    float* row = io + (size_t)t * DM;
    float2 x = *(const float2*)&row[tid * 2];
    float s  = x.x + x.y;
    float ss = fmaf(x.x, x.x, x.y * x.y);
    #pragma unroll
    for (int o = 1; o < 64; o <<= 1) {
        s  += __shfl_xor(s,  o, 64);
        ss += __shfl_xor(ss, o, 64);
    }
    __shared__ float wsum[4], wsq[4];
    const int w = tid >> 6;
    if ((tid & 63) == 0) { wsum[w] = s; wsq[w] = ss; }
    __syncthreads();
    s  = wsum[0] + wsum[1] + wsum[2] + wsum[3];
    ss = wsq[0]  + wsq[1]  + wsq[2]  + wsq[3];
    const float mean = s * (1.0f / DM);
    const float var  = ss * (1.0f / DM) - mean * mean;
    const float rstd = rsqrtf(var + 1e-6f);
    float2 gg = *(const float2*)&g[tid * 2];
    float2 bv = *(const float2*)&bb[tid * 2];
    x.x = (x.x - mean) * rstd * gg.x + bv.x;
    x.y = (x.y - mean) * rstd * gg.y + bv.y;
    *(float2*)&row[tid * 2] = x;
}

// ---------------------------------------------------------------------------
extern "C" void kernel_launch(void* const* d_in, const int* in_sizes, int n_in,
                              void* d_out, int out_size, void* d_ws, size_t ws_size,
                              hipStream_t stream)
{
    (void)in_sizes; (void)n_in; (void)out_size; (void)ws_size;
    const float* hidden = (const float*)d_in[0];
    const float* rpe    = (const float*)d_in[1];
    const float* Wq     = (const float*)d_in[2];
    const float* Wk     = (const float*)d_in[3];
    const float* Wv     = (const float*)d_in[4];
    const float* fc_w   = (const float*)d_in[5];
    const float* fc_b   = (const float*)d_in[6];
    const float* ln_g   = (const float*)d_in[7];
    const float* ln_b   = (const float*)d_in[8];
    float* out = (float*)d_out;
    char* ws = (char*)d_ws;

    const size_t MB = 1024 * 1024;
    unsigned short* hb  = (unsigned short*)(ws + 0 * MB);    // 8 MB
    unsigned short* wq  = (unsigned short*)(ws + 8 * MB);
    unsigned short* wk  = (unsigned short*)(ws + 8 * MB + 512 * 1024);
    unsigned short* wv  = (unsigned short*)(ws + 9 * MB);
    unsigned short* wf  = (unsigned short*)(ws + 9 * MB + 512 * 1024);
    unsigned short* qB  = (unsigned short*)(ws + 16 * MB);   // 8 MB [B,H,N,64]
    unsigned short* kB  = (unsigned short*)(ws + 24 * MB);   // 8 MB [B,H,N,64]
    unsigned short* vtB = (unsigned short*)(ws + 32 * MB);   // 8 MB [B,H,64,N]
    unsigned short* cb  = (unsigned short*)(ws + 40 * MB);   // 8 MB ctx

    CastArgs ca;
    ca.src[0] = hidden; ca.dst[0] = hb; ca.n[0] = B_ * N_ * DM;
    ca.src[1] = Wq;     ca.dst[1] = wq; ca.n[1] = DM * DM;
    ca.src[2] = Wk;     ca.dst[2] = wk; ca.n[2] = DM * DM;
    ca.src[3] = Wv;     ca.dst[3] = wv; ca.n[3] = DM * DM;
    ca.src[4] = fc_w;   ca.dst[4] = wf; ca.n[4] = DM * DM;
    cast_bf16_kernel<<<dim3(2048, 5), 256, 0, stream>>>(ca);

    qkv_gemm_kernel<<<dim3(64, 12), 256, 0, stream>>>(hb, wq, wk, wv, qB, kB, vtB);
    attn_kernel<<<dim3(16, H_, B_), 256, 0, stream>>>(qB, kB, vtB, rpe, cb);
    fc_gemm_kernel<<<dim3(64, 4), 256, 0, stream>>>(cb, wf, fc_b, hidden, out);
    ln_kernel<<<B_ * N_, 256, 0, stream>>>(out, ln_g, ln_b);
}